// Round 4
// baseline (173.029 us; speedup 1.0000x reference)
//
#include <hip/hip_runtime.h>
#include <math.h>
#include <stdint.h>

typedef __attribute__((ext_vector_type(8))) __bf16 bf16x8;
typedef __attribute__((ext_vector_type(16))) float f32x16;

#define Z16 {0.f,0.f,0.f,0.f,0.f,0.f,0.f,0.f,0.f,0.f,0.f,0.f,0.f,0.f,0.f,0.f}

__device__ __forceinline__ unsigned short f2b(float f) {
  union { float f; uint32_t u; } v; v.f = f;
  uint32_t r = (v.u + 0x7FFFu + ((v.u >> 16) & 1u)) >> 16;
  return (unsigned short)r;
}
__device__ __forceinline__ float b2f(unsigned short u) {
  union { uint32_t u; float f; } v; v.u = ((uint32_t)u) << 16;
  return v.f;
}
__device__ __forceinline__ uint32_t pk2(float a, float b) {
  return (uint32_t)f2b(a) | ((uint32_t)f2b(b) << 16);
}
__device__ __forceinline__ void glds16(const void* g, void* l) {
  __builtin_amdgcn_global_load_lds(
      (const __attribute__((address_space(1))) void*)g,
      (__attribute__((address_space(3))) void*)l, 16, 0, 0);
}
#define MFMA32(a, b, c) __builtin_amdgcn_mfma_f32_32x32x16_bf16(a, b, c, 0, 0, 0)

// ===================== fp32 -> bf16 =====================
__global__ __launch_bounds__(256) void cvt32to16(
    const float* __restrict__ in, unsigned short* __restrict__ out, int n8) {
  int i = blockIdx.x * 256 + threadIdx.x;
  if (i < n8) {
    float4 a = ((const float4*)in)[i * 2];
    float4 b = ((const float4*)in)[i * 2 + 1];
    uint4 o;
    o.x = pk2(a.x, a.y); o.y = pk2(a.z, a.w);
    o.z = pk2(b.x, b.y); o.w = pk2(b.z, b.w);
    ((uint4*)out)[i] = o;
  }
}

// ====== weight transpose+convert: f32 [K][N] -> bf16 [N][K] ======
__global__ __launch_bounds__(256) void transpose_cvt(
    const float* __restrict__ in, unsigned short* __restrict__ out,
    int ldin, int ldout) {
  __shared__ float T[64][68];
  const int k0 = blockIdx.x * 64, n0 = blockIdx.y * 64;
  const int t = threadIdx.x;
  const int r = t >> 2, c16 = (t & 3) * 16;
  #pragma unroll
  for (int i = 0; i < 4; ++i) {
    float4 v = *(const float4*)&in[(size_t)(k0 + r) * ldin + n0 + c16 + i * 4];
    *(float4*)&T[r][c16 + i * 4] = v;
  }
  __syncthreads();
  const int n = t >> 2, k16 = (t & 3) * 16;
  uint32_t w[8];
  #pragma unroll
  for (int p = 0; p < 8; ++p)
    w[p] = pk2(T[k16 + 2 * p][n], T[k16 + 2 * p + 1][n]);
  uint4 o0; o0.x = w[0]; o0.y = w[1]; o0.z = w[2]; o0.w = w[3];
  uint4 o1; o1.x = w[4]; o1.y = w[5]; o1.z = w[6]; o1.w = w[7];
  *(uint4*)&out[(size_t)(n0 + n) * ldout + k0 + k16] = o0;
  *(uint4*)&out[(size_t)(n0 + n) * ldout + k0 + k16 + 8] = o1;
}

// ===================== GEMM: 128x64 tile, BK=64, 32x32x16 MFMA =====================
// C[M,N] = A[M,K] @ Bt[N,K]^T. 4 waves, wave tile 32m x 64n. Linear LDS (m97 pattern).
// EPI: 0 bias->bf16 | 1 bias,relu,+res->bf16 | 2 bias,relu->bf16
//      3 bias,+res->f32 | 5 accumulate f32
template <int EPI>
__global__ __launch_bounds__(256, 2) void gemm2(
    const unsigned short* __restrict__ A, int lda,
    const unsigned short* __restrict__ Bt, int ldb,
    const float* __restrict__ bias,
    const unsigned short* __restrict__ res, int ldr,
    void* __restrict__ Cout, int ldc, int K) {
  __shared__ __align__(16) unsigned short As[128 * 64];
  __shared__ __align__(16) unsigned short Bs[64 * 64];
  const int tid = threadIdx.x, lane = tid & 63, wid = tid >> 6;
  const int l31 = lane & 31, g2 = lane >> 5;
  const int m0 = blockIdx.x * 128, n0 = blockIdx.y * 64;

  const char* srcA[4];
  const char* srcB[2];
  #pragma unroll
  for (int p = 0; p < 4; ++p) {
    int row = p * 32 + wid * 8 + (lane >> 3);
    srcA[p] = (const char*)A + ((size_t)(m0 + row) * lda) * 2 + (lane & 7) * 16;
  }
  #pragma unroll
  for (int p = 0; p < 2; ++p) {
    int row = p * 32 + wid * 8 + (lane >> 3);
    srcB[p] = (const char*)Bt + ((size_t)(n0 + row) * ldb) * 2 + (lane & 7) * 16;
  }

  f32x16 acc0 = Z16, acc1 = Z16;

  for (int k0 = 0; k0 < K; k0 += 64) {
    __syncthreads();
    #pragma unroll
    for (int p = 0; p < 4; ++p) {
      glds16(srcA[p], &As[p * 2048 + wid * 512]);
      srcA[p] += 128;
    }
    #pragma unroll
    for (int p = 0; p < 2; ++p) {
      glds16(srcB[p], &Bs[p * 2048 + wid * 512]);
      srcB[p] += 128;
    }
    __syncthreads();
    #pragma unroll
    for (int kc = 0; kc < 4; ++kc) {
      const int xo = kc * 32 + g2 * 16;
      bf16x8 af = *(const bf16x8*)((const char*)As + (wid * 32 + l31) * 128 + xo);
      bf16x8 b0v = *(const bf16x8*)((const char*)Bs + l31 * 128 + xo);
      bf16x8 b1v = *(const bf16x8*)((const char*)Bs + (32 + l31) * 128 + xo);
      acc0 = MFMA32(af, b0v, acc0);
      acc1 = MFMA32(af, b1v, acc1);
    }
  }

  #pragma unroll
  for (int nb = 0; nb < 2; ++nb) {
    const f32x16& acc = nb ? acc1 : acc0;
    const int col = n0 + nb * 32 + l31;
    const float bs = (EPI == 5) ? 0.f : bias[col];
    #pragma unroll
    for (int r = 0; r < 16; ++r) {
      const int m = m0 + wid * 32 + (r & 3) + 8 * (r >> 2) + 4 * g2;
      float v = acc[r] + bs;
      if (EPI == 1 || EPI == 2) v = fmaxf(v, 0.f);
      if (EPI == 1 || EPI == 3) v += b2f(res[(size_t)m * ldr + col]);
      if (EPI == 0 || EPI == 1 || EPI == 2)
        ((unsigned short*)Cout)[(size_t)m * ldc + col] = f2b(v);
      else if (EPI == 3)
        ((float*)Cout)[(size_t)m * ldc + col] = v;
      else if (EPI == 5)
        ((float*)Cout)[(size_t)m * ldc + col] += v;
    }
  }
}

// ===================== attention: 32x32 MFMA flash =====================
// grid (16 qtiles, 8 heads, 4 batch); 4 waves, wave owns 32 q-rows; KVBLK=64.
// O1 = Qproj + softmax(Q K^T / sqrt(32)) @ V. Manual padded LDS staging.
#define KLD 40  // K tile row stride (shorts): 80B, 16B-aligned, 4-way banks
#define VLD 72  // V^T row stride (shorts): 144B, 16B-aligned, 4-way banks
__global__ __launch_bounds__(256, 2) void attn2(
    const unsigned short* __restrict__ Qg,   // [8192][256]
    const unsigned short* __restrict__ Kg,   // [8192][256]
    const unsigned short* __restrict__ Vg,   // [8192][256]
    unsigned short* __restrict__ O1) {       // [8192][256]
  __shared__ __align__(16) unsigned short Ks[64 * KLD];
  __shared__ __align__(16) unsigned short Vs[32 * VLD];
  const int tid = threadIdx.x, lane = tid & 63, wid = tid >> 6;
  const int l31 = lane & 31, g2 = lane >> 5;
  const int qt = blockIdx.x, h = blockIdx.y, b = blockIdx.z;
  const int row0 = b * 2048 + qt * 128;
  const int qrow = row0 + wid * 32 + l31;

  // Q fragments (B-operand), pre-scaled by 1/sqrt(32)*log2(e)
  const float SCL2 = 0.17677669529663687f * 1.4426950408889634f;
  bf16x8 qf0, qf1;
  {
    const unsigned short* qp = Qg + (size_t)qrow * 256 + h * 32 + g2 * 8;
    #pragma unroll
    for (int dc = 0; dc < 2; ++dc) {
      ushort4 r0 = *(const ushort4*)(qp + dc * 16);
      ushort4 r1 = *(const ushort4*)(qp + dc * 16 + 4);
      union { unsigned short s[8]; bf16x8 v; } u;
      u.s[0] = f2b(b2f(r0.x) * SCL2); u.s[1] = f2b(b2f(r0.y) * SCL2);
      u.s[2] = f2b(b2f(r0.z) * SCL2); u.s[3] = f2b(b2f(r0.w) * SCL2);
      u.s[4] = f2b(b2f(r1.x) * SCL2); u.s[5] = f2b(b2f(r1.y) * SCL2);
      u.s[6] = f2b(b2f(r1.z) * SCL2); u.s[7] = f2b(b2f(r1.w) * SCL2);
      if (dc == 0) qf0 = u.v; else qf1 = u.v;
    }
  }

  // staging pointers
  const int ksr = tid >> 2, ksc = (tid & 3) * 8;        // K: row, col8
  const unsigned short* srcK =
      Kg + (size_t)(b * 2048 + ksr) * 256 + h * 32 + ksc;
  const int vd = tid & 31, vk = (tid >> 5) * 8;          // V: d, k8
  const unsigned short* srcV =
      Vg + (size_t)(b * 2048 + vk) * 256 + h * 32 + vd;

  f32x16 oacc = Z16;
  float mrun = -INFINITY, lrun = 0.f;

  for (int kt = 0; kt < 2048; kt += 64) {
    __syncthreads();
    // K stage: [64][KLD], 16B-aligned vector write
    {
      uint4 kv = *(const uint4*)srcK;
      srcK += 64 * 256;
      *(uint4*)&Ks[ksr * KLD + ksc] = kv;
    }
    // V^T stage: 8 strided loads -> [32][VLD]
    {
      unsigned short e0 = srcV[0 * 256], e1 = srcV[1 * 256];
      unsigned short e2 = srcV[2 * 256], e3 = srcV[3 * 256];
      unsigned short e4 = srcV[4 * 256], e5 = srcV[5 * 256];
      unsigned short e6 = srcV[6 * 256], e7 = srcV[7 * 256];
      srcV += 64 * 256;
      uint4 w;
      w.x = (uint32_t)e0 | ((uint32_t)e1 << 16);
      w.y = (uint32_t)e2 | ((uint32_t)e3 << 16);
      w.z = (uint32_t)e4 | ((uint32_t)e5 << 16);
      w.w = (uint32_t)e6 | ((uint32_t)e7 << 16);
      *(uint4*)&Vs[vd * VLD + vk] = w;
    }
    __syncthreads();

    // S^T = K @ Q^T (pre-scaled, log2 domain): rows k, cols q
    f32x16 p0 = Z16, p1 = Z16;
    {
      bf16x8 k00 = *(const bf16x8*)&Ks[l31 * KLD + g2 * 8];
      bf16x8 k01 = *(const bf16x8*)&Ks[l31 * KLD + 16 + g2 * 8];
      bf16x8 k10 = *(const bf16x8*)&Ks[(32 + l31) * KLD + g2 * 8];
      bf16x8 k11 = *(const bf16x8*)&Ks[(32 + l31) * KLD + 16 + g2 * 8];
      p0 = MFMA32(k00, qf0, p0);
      p0 = MFMA32(k01, qf1, p0);
      p1 = MFMA32(k10, qf0, p1);
      p1 = MFMA32(k11, qf1, p1);
    }

    // online softmax over k (rows); lane holds 32 of 64, pair via xor32
    float tmax = p0[0];
    #pragma unroll
    for (int i = 1; i < 16; ++i) tmax = fmaxf(tmax, p0[i]);
    #pragma unroll
    for (int i = 0; i < 16; ++i) tmax = fmaxf(tmax, p1[i]);
    tmax = fmaxf(tmax, __shfl_xor(tmax, 32));
    const float mnew = fmaxf(mrun, tmax);
    const float corr = __builtin_amdgcn_exp2f(mrun - mnew);
    float rsum = 0.f;
    #pragma unroll
    for (int i = 0; i < 16; ++i) { p0[i] = __builtin_amdgcn_exp2f(p0[i] - mnew); rsum += p0[i]; }
    #pragma unroll
    for (int i = 0; i < 16; ++i) { p1[i] = __builtin_amdgcn_exp2f(p1[i] - mnew); rsum += p1[i]; }
    rsum += __shfl_xor(rsum, 32);
    lrun = lrun * corr + rsum;
    mrun = mnew;
    #pragma unroll
    for (int i = 0; i < 16; ++i) oacc[i] *= corr;

    // PV: O^T += V^T @ P^T  (B-slot (t,g2) of chunk c' holds k=16c'+8g2+t)
    #pragma unroll
    for (int rb = 0; rb < 2; ++rb) {
      const f32x16& pp = rb ? p1 : p0;
      #pragma unroll
      for (int c = 0; c < 2; ++c) {
        uint32_t A0 = pk2(pp[8 * c + 0], pp[8 * c + 1]);
        uint32_t A1 = pk2(pp[8 * c + 2], pp[8 * c + 3]);
        uint32_t B0 = pk2(pp[8 * c + 4], pp[8 * c + 5]);
        uint32_t B1 = pk2(pp[8 * c + 6], pp[8 * c + 7]);
        uint32_t pA0 = (uint32_t)__shfl_xor((int)A0, 32);
        uint32_t pB0 = (uint32_t)__shfl_xor((int)B0, 32);
        uint32_t pA1 = (uint32_t)__shfl_xor((int)A1, 32);
        uint32_t pB1 = (uint32_t)__shfl_xor((int)B1, 32);
        union { uint32_t u[4]; bf16x8 v; } fr;
        fr.u[0] = g2 ? pB0 : A0;
        fr.u[1] = g2 ? pB1 : A1;
        fr.u[2] = g2 ? B0 : pA0;
        fr.u[3] = g2 ? B1 : pA1;
        bf16x8 vf = *(const bf16x8*)&Vs[l31 * VLD + rb * 32 + c * 16 + g2 * 8];
        oacc = MFMA32(vf, fr.v, oacc);
      }
    }
  }

  // epilogue: O1 = Q + O^T/l  (lane: q-row=qrow, d = 8j+4g2+{0..3})
  const float inv = 1.f / lrun;
  const unsigned short* qres = Qg + (size_t)qrow * 256 + h * 32;
  unsigned short* op = O1 + (size_t)qrow * 256 + h * 32;
  #pragma unroll
  for (int j = 0; j < 4; ++j) {
    const int d0 = 8 * j + 4 * g2;
    uint2 qv = *(const uint2*)(qres + d0);
    float r0 = b2f((unsigned short)(qv.x & 0xffff)) + oacc[4 * j + 0] * inv;
    float r1 = b2f((unsigned short)(qv.x >> 16))    + oacc[4 * j + 1] * inv;
    float r2 = b2f((unsigned short)(qv.y & 0xffff)) + oacc[4 * j + 2] * inv;
    float r3 = b2f((unsigned short)(qv.y >> 16))    + oacc[4 * j + 3] * inv;
    uint2 w; w.x = pk2(r0, r1); w.y = pk2(r2, r3);
    *(uint2*)(op + d0) = w;
  }
}

// ===================== LayerNorm (bf16 in/out) =====================
__global__ __launch_bounds__(256) void ln_k(
    const unsigned short* __restrict__ X, const float* __restrict__ gw,
    const float* __restrict__ bw, unsigned short* __restrict__ Y) {
  const int wid = threadIdx.x >> 6, lane = threadIdx.x & 63;
  const int row = blockIdx.x * 4 + wid;
  ushort4 xv = *(const ushort4*)(X + (size_t)row * 256 + lane * 4);
  float x0 = b2f(xv.x), x1 = b2f(xv.y), x2 = b2f(xv.z), x3 = b2f(xv.w);
  float s = x0 + x1 + x2 + x3;
  float sq = x0 * x0 + x1 * x1 + x2 * x2 + x3 * x3;
  #pragma unroll
  for (int off = 32; off >= 1; off >>= 1) {
    s += __shfl_xor(s, off);
    sq += __shfl_xor(sq, off);
  }
  const float mean = s * (1.f / 256.f);
  const float var = sq * (1.f / 256.f) - mean * mean;
  const float rstd = rsqrtf(var + 1e-5f);
  float4 gv = *(const float4*)&gw[lane * 4];
  float4 bv = *(const float4*)&bw[lane * 4];
  ushort4 o;
  o.x = f2b((x0 - mean) * rstd * gv.x + bv.x);
  o.y = f2b((x1 - mean) * rstd * gv.y + bv.y);
  o.z = f2b((x2 - mean) * rstd * gv.z + bv.z);
  o.w = f2b((x3 - mean) * rstd * gv.w + bv.w);
  *(ushort4*)(Y + (size_t)row * 256 + lane * 4) = o;
}

// ===================== launch =====================
extern "C" void kernel_launch(void* const* d_in, const int* in_sizes, int n_in,
                              void* d_out, int out_size, void* d_ws, size_t ws_size,
                              hipStream_t stream) {
  (void)in_sizes; (void)n_in; (void)out_size; (void)ws_size;
  const float* q = (const float*)d_in[0];
  const float* x = (const float*)d_in[1];
  const float* Wq = (const float*)d_in[2];
  const float* bq = (const float*)d_in[3];
  const float* Wk = (const float*)d_in[4];
  const float* bk = (const float*)d_in[5];
  const float* Wv = (const float*)d_in[6];
  const float* bv = (const float*)d_in[7];
  const float* Wo = (const float*)d_in[8];
  const float* bo = (const float*)d_in[9];
  const float* Wm = (const float*)d_in[10];
  const float* bm = (const float*)d_in[11];
  const float* We = (const float*)d_in[12];
  const float* be = (const float*)d_in[13];
  const float* g0 = (const float*)d_in[14];
  const float* b0 = (const float*)d_in[15];
  const float* g1 = (const float*)d_in[16];
  const float* b1 = (const float*)d_in[17];
  float* out = (float*)d_out;

  uint8_t* ws = (uint8_t*)d_ws;
  unsigned short* WqT = (unsigned short*)(ws + 0);        // 128 KB
  unsigned short* WkT = (unsigned short*)(ws + 131072);   // 128 KB
  unsigned short* WvT = (unsigned short*)(ws + 262144);   // 128 KB
  unsigned short* WoT = (unsigned short*)(ws + 393216);   // 128 KB
  unsigned short* WmT = (unsigned short*)(ws + 524288);   // 512 KB
  unsigned short* WeT = (unsigned short*)(ws + 1048576);  // 512 KB
  // activation regions (4 MB each)
  unsigned short* qh  = (unsigned short*)(ws + 1572864);   // A: qh -> O1n
  unsigned short* xh  = (unsigned short*)(ws + 5767168);   // B: xh -> O2
  unsigned short* Qb  = (unsigned short*)(ws + 9961472);   // C: Qb -> O2n
  unsigned short* Kb  = (unsigned short*)(ws + 14155776);  // D: Kb -> Mb(lo)
  unsigned short* Vb  = (unsigned short*)(ws + 18350080);  // E: Vb -> Mb(hi)
  unsigned short* O1  = (unsigned short*)(ws + 22544384);  // F
  unsigned short* O1n = qh;
  unsigned short* O2  = xh;
  unsigned short* O2n = Qb;
  unsigned short* Mb  = Kb;  // 8 MB spanning D+E

  // conversions
  cvt32to16<<<1024, 256, 0, stream>>>(q, qh, 262144);
  cvt32to16<<<1024, 256, 0, stream>>>(x, xh, 262144);
  transpose_cvt<<<dim3(4, 4), 256, 0, stream>>>(Wq, WqT, 256, 256);
  transpose_cvt<<<dim3(4, 4), 256, 0, stream>>>(Wk, WkT, 256, 256);
  transpose_cvt<<<dim3(4, 4), 256, 0, stream>>>(Wv, WvT, 256, 256);
  transpose_cvt<<<dim3(4, 4), 256, 0, stream>>>(Wo, WoT, 256, 256);
  transpose_cvt<<<dim3(4, 16), 256, 0, stream>>>(Wm, WmT, 1024, 256);
  transpose_cvt<<<dim3(16, 4), 256, 0, stream>>>(We, WeT, 256, 1024);

  // projections
  gemm2<0><<<dim3(64, 4), 256, 0, stream>>>(qh, 256, WqT, 256, bq, nullptr, 0, Qb, 256, 256);
  gemm2<0><<<dim3(64, 4), 256, 0, stream>>>(xh, 256, WkT, 256, bk, nullptr, 0, Kb, 256, 256);
  gemm2<0><<<dim3(64, 4), 256, 0, stream>>>(xh, 256, WvT, 256, bv, nullptr, 0, Vb, 256, 256);

  // attention + residual
  attn2<<<dim3(16, 8, 4), 256, 0, stream>>>(Qb, Kb, Vb, O1);

  // LN0
  ln_k<<<2048, 256, 0, stream>>>(O1, g0, b0, O1n);
  // O2 = O1n + relu(O1n @ Wo + bo)
  gemm2<1><<<dim3(64, 4), 256, 0, stream>>>(O1n, 256, WoT, 256, bo, O1n, 256, O2, 256, 256);
  // LN1
  ln_k<<<2048, 256, 0, stream>>>(O2, g1, b1, O2n);

  // MLP in two F-chunks of 512
  for (int c = 0; c < 2; ++c) {
    gemm2<2><<<dim3(64, 8), 256, 0, stream>>>(
        O2n, 256, WmT + (size_t)c * 512 * 256, 256, bm + c * 512, nullptr, 0,
        Mb, 512, 256);
    if (c == 0)
      gemm2<3><<<dim3(64, 4), 256, 0, stream>>>(
          Mb, 512, WeT, 1024, be, O2, 256, out, 256, 512);
    else
      gemm2<5><<<dim3(64, 4), 256, 0, stream>>>(
          Mb, 512, WeT + 512, 1024, nullptr, nullptr, 0, out, 256, 512);
  }
}

// Round 5
// 128.869 us; speedup vs baseline: 1.3427x; 1.3427x over previous
//
#include <hip/hip_runtime.h>
#include <math.h>
#include <stdint.h>

typedef __attribute__((ext_vector_type(8))) __bf16 bf16x8;
typedef __attribute__((ext_vector_type(16))) float f32x16;

#define Z16 {0.f,0.f,0.f,0.f,0.f,0.f,0.f,0.f,0.f,0.f,0.f,0.f,0.f,0.f,0.f,0.f}

__device__ __forceinline__ unsigned short f2b(float f) {
  union { float f; uint32_t u; } v; v.f = f;
  uint32_t r = (v.u + 0x7FFFu + ((v.u >> 16) & 1u)) >> 16;
  return (unsigned short)r;
}
__device__ __forceinline__ float b2f(unsigned short u) {
  union { uint32_t u; float f; } v; v.u = ((uint32_t)u) << 16;
  return v.f;
}
__device__ __forceinline__ uint32_t pk2(float a, float b) {
  return (uint32_t)f2b(a) | ((uint32_t)f2b(b) << 16);
}
__device__ __forceinline__ uint32_t cvtpk(float lo, float hi) {
  uint32_t r;
  asm("v_cvt_pk_bf16_f32 %0, %1, %2" : "=v"(r) : "v"(lo), "v"(hi));
  return r;
}
__device__ __forceinline__ void glds16(const void* g, void* l) {
  __builtin_amdgcn_global_load_lds(
      (const __attribute__((address_space(1))) void*)g,
      (__attribute__((address_space(3))) void*)l, 16, 0, 0);
}
#define MFMA32(a, b, c) __builtin_amdgcn_mfma_f32_32x32x16_bf16(a, b, c, 0, 0, 0)

// ===================== fused preprocessing =====================
// blocks [0,2048): fp32->bf16 cvt of q (0..1023) and x (1024..2047)
// blocks [2048,2240): weight transpose+convert tiles
// block 2240: bias pack bk||bv -> bkv
__global__ __launch_bounds__(256) void prep(
    const float* __restrict__ q, const float* __restrict__ x,
    unsigned short* __restrict__ qh, unsigned short* __restrict__ xh,
    const float* __restrict__ Wq, const float* __restrict__ Wk,
    const float* __restrict__ Wv, const float* __restrict__ Wo,
    const float* __restrict__ Wm, const float* __restrict__ We,
    unsigned short* __restrict__ WqT, unsigned short* __restrict__ WkvT,
    unsigned short* __restrict__ WoT, unsigned short* __restrict__ WmT,
    unsigned short* __restrict__ WeT,
    const float* __restrict__ bk, const float* __restrict__ bv,
    float* __restrict__ bkv) {
  __shared__ float T[64][68];
  const int bx = blockIdx.x, tid = threadIdx.x;
  if (bx < 2048) {
    const float* src = (bx < 1024) ? q : x;
    unsigned short* dst = (bx < 1024) ? qh : xh;
    const int i = (bx & 1023) * 256 + tid;
    float4 a = ((const float4*)src)[i * 2];
    float4 b = ((const float4*)src)[i * 2 + 1];
    uint4 o;
    o.x = pk2(a.x, a.y); o.y = pk2(a.z, a.w);
    o.z = pk2(b.x, b.y); o.w = pk2(b.z, b.w);
    ((uint4*)dst)[i] = o;
  } else if (bx < 2240) {
    int t = bx - 2048;
    const float* in; unsigned short* out; int ldin, ldout, kx, nx;
    if (t < 16)       { in = Wq; out = WqT;           ldin = 256;  ldout = 256;  kx = t & 3;  nx = t >> 2; }
    else if (t < 32)  { t -= 16;  in = Wk; out = WkvT;          ldin = 256;  ldout = 256;  kx = t & 3;  nx = t >> 2; }
    else if (t < 48)  { t -= 32;  in = Wv; out = WkvT + 65536;  ldin = 256;  ldout = 256;  kx = t & 3;  nx = t >> 2; }
    else if (t < 64)  { t -= 48;  in = Wo; out = WoT;           ldin = 256;  ldout = 256;  kx = t & 3;  nx = t >> 2; }
    else if (t < 128) { t -= 64;  in = Wm; out = WmT;           ldin = 1024; ldout = 256;  kx = t & 3;  nx = t >> 2; }
    else              { t -= 128; in = We; out = WeT;           ldin = 256;  ldout = 1024; kx = t & 15; nx = t >> 4; }
    const int k0 = kx * 64, n0 = nx * 64;
    const int r = tid >> 2, c16 = (tid & 3) * 16;
    #pragma unroll
    for (int i = 0; i < 4; ++i)
      *(float4*)&T[r][c16 + i * 4] =
          *(const float4*)&in[(size_t)(k0 + r) * ldin + n0 + c16 + i * 4];
    __syncthreads();
    const int n = tid >> 2, k16 = (tid & 3) * 16;
    uint32_t wb[8];
    #pragma unroll
    for (int p = 0; p < 8; ++p)
      wb[p] = pk2(T[k16 + 2 * p][n], T[k16 + 2 * p + 1][n]);
    uint4 o0, o1;
    o0.x = wb[0]; o0.y = wb[1]; o0.z = wb[2]; o0.w = wb[3];
    o1.x = wb[4]; o1.y = wb[5]; o1.z = wb[6]; o1.w = wb[7];
    *(uint4*)&out[(size_t)(n0 + n) * ldout + k0 + k16] = o0;
    *(uint4*)&out[(size_t)(n0 + n) * ldout + k0 + k16 + 8] = o1;
  } else {
    if (tid < 256) { bkv[tid] = bk[tid]; bkv[256 + tid] = bv[tid]; }
  }
}

// ===================== GEMM big: 128x64 tile, BK=64, dbuf 2-phase =====================
// C[M,N] = A[M,K] @ Bt[N,K]^T. 4 waves, wave tile 32m x 64n.
// EPI: 0 bias->bf16 | 1 bias,relu,+res->bf16 | 2 bias,relu->bf16 | 3 bias,+res->f32
template <int EPI>
__global__ __launch_bounds__(256, 2) void gemm_big(
    const unsigned short* __restrict__ A, int lda,
    const unsigned short* __restrict__ Bt, int ldb,
    const float* __restrict__ bias,
    const unsigned short* __restrict__ res, int ldr,
    void* __restrict__ Cout, int ldc, int K) {
  __shared__ __align__(16) unsigned short As[2 * 128 * 64];
  __shared__ __align__(16) unsigned short Bs[2 * 64 * 64];
  const int tid = threadIdx.x, lane = tid & 63, wid = tid >> 6;
  const int l31 = lane & 31, g2 = lane >> 5;
  const int m0 = blockIdx.x * 128, n0 = blockIdx.y * 64;

  const char* srcA[4];
  const char* srcB[2];
  #pragma unroll
  for (int p = 0; p < 4; ++p) {
    int row = p * 32 + wid * 8 + (lane >> 3);
    srcA[p] = (const char*)A + ((size_t)(m0 + row) * lda) * 2 + (lane & 7) * 16;
  }
  #pragma unroll
  for (int p = 0; p < 2; ++p) {
    int row = p * 32 + wid * 8 + (lane >> 3);
    srcB[p] = (const char*)Bt + ((size_t)(n0 + row) * ldb) * 2 + (lane & 7) * 16;
  }

  f32x16 acc0 = Z16, acc1 = Z16;
  const int nt = K >> 6;

  // prologue: stage tile 0 into buf 0
  #pragma unroll
  for (int p = 0; p < 4; ++p) { glds16(srcA[p], &As[p * 2048 + wid * 512]); srcA[p] += 128; }
  #pragma unroll
  for (int p = 0; p < 2; ++p) { glds16(srcB[p], &Bs[p * 2048 + wid * 512]); srcB[p] += 128; }
  __syncthreads();

  for (int t = 0; t < nt; ++t) {
    const int cur = t & 1, nxt = cur ^ 1;
    if (t + 1 < nt) {
      #pragma unroll
      for (int p = 0; p < 4; ++p) { glds16(srcA[p], &As[nxt * 8192 + p * 2048 + wid * 512]); srcA[p] += 128; }
      #pragma unroll
      for (int p = 0; p < 2; ++p) { glds16(srcB[p], &Bs[nxt * 4096 + p * 2048 + wid * 512]); srcB[p] += 128; }
    }
    const char* as = (const char*)As + cur * 16384;
    const char* bs = (const char*)Bs + cur * 8192;
    #pragma unroll
    for (int kc = 0; kc < 4; ++kc) {
      const int xo = kc * 32 + g2 * 16;
      bf16x8 af  = *(const bf16x8*)(as + (wid * 32 + l31) * 128 + xo);
      bf16x8 b0v = *(const bf16x8*)(bs + l31 * 128 + xo);
      bf16x8 b1v = *(const bf16x8*)(bs + (32 + l31) * 128 + xo);
      acc0 = MFMA32(af, b0v, acc0);
      acc1 = MFMA32(af, b1v, acc1);
    }
    __syncthreads();  // drains prefetch vmcnt + compute lgkm; one barrier per K-step
  }

  #pragma unroll
  for (int nb = 0; nb < 2; ++nb) {
    const f32x16& acc = nb ? acc1 : acc0;
    const int col = n0 + nb * 32 + l31;
    const float bs = bias[col];
    #pragma unroll
    for (int r = 0; r < 16; ++r) {
      const int m = m0 + wid * 32 + (r & 3) + 8 * (r >> 2) + 4 * g2;
      float v = acc[r] + bs;
      if (EPI == 1 || EPI == 2) v = fmaxf(v, 0.f);
      if (EPI == 1 || EPI == 3) v += b2f(res[(size_t)m * ldr + col]);
      if (EPI == 3)
        ((float*)Cout)[(size_t)m * ldc + col] = v;
      else
        ((unsigned short*)Cout)[(size_t)m * ldc + col] = f2b(v);
    }
  }
}

// ===================== GEMM small: 64x64 tile, BK=64, dbuf 2-phase =====================
// 4 waves, wave tile 32x32 quadrant.
template <int EPI>
__global__ __launch_bounds__(256, 2) void gemm_small(
    const unsigned short* __restrict__ A, int lda,
    const unsigned short* __restrict__ Bt, int ldb,
    const float* __restrict__ bias,
    const unsigned short* __restrict__ res, int ldr,
    void* __restrict__ Cout, int ldc, int K) {
  __shared__ __align__(16) unsigned short As[2 * 64 * 64];
  __shared__ __align__(16) unsigned short Bs[2 * 64 * 64];
  const int tid = threadIdx.x, lane = tid & 63, wid = tid >> 6;
  const int l31 = lane & 31, g2 = lane >> 5;
  const int m0 = blockIdx.x * 64, n0 = blockIdx.y * 64;
  const int wr = (wid >> 1) * 32, wc = (wid & 1) * 32;

  const char* srcA[2];
  const char* srcB[2];
  #pragma unroll
  for (int p = 0; p < 2; ++p) {
    int row = p * 32 + wid * 8 + (lane >> 3);
    srcA[p] = (const char*)A + ((size_t)(m0 + row) * lda) * 2 + (lane & 7) * 16;
    srcB[p] = (const char*)Bt + ((size_t)(n0 + row) * ldb) * 2 + (lane & 7) * 16;
  }

  f32x16 acc = Z16;
  const int nt = K >> 6;

  #pragma unroll
  for (int p = 0; p < 2; ++p) {
    glds16(srcA[p], &As[p * 2048 + wid * 512]); srcA[p] += 128;
    glds16(srcB[p], &Bs[p * 2048 + wid * 512]); srcB[p] += 128;
  }
  __syncthreads();

  for (int t = 0; t < nt; ++t) {
    const int cur = t & 1, nxt = cur ^ 1;
    if (t + 1 < nt) {
      #pragma unroll
      for (int p = 0; p < 2; ++p) {
        glds16(srcA[p], &As[nxt * 4096 + p * 2048 + wid * 512]); srcA[p] += 128;
        glds16(srcB[p], &Bs[nxt * 4096 + p * 2048 + wid * 512]); srcB[p] += 128;
      }
    }
    const char* as = (const char*)As + cur * 8192;
    const char* bs = (const char*)Bs + cur * 8192;
    #pragma unroll
    for (int kc = 0; kc < 4; ++kc) {
      const int xo = kc * 32 + g2 * 16;
      bf16x8 af = *(const bf16x8*)(as + (wr + l31) * 128 + xo);
      bf16x8 bf = *(const bf16x8*)(bs + (wc + l31) * 128 + xo);
      acc = MFMA32(af, bf, acc);
    }
    __syncthreads();
  }

  const int col = n0 + wc + l31;
  const float bs = bias[col];
  #pragma unroll
  for (int r = 0; r < 16; ++r) {
    const int m = m0 + wr + (r & 3) + 8 * (r >> 2) + 4 * g2;
    float v = acc[r] + bs;
    if (EPI == 1 || EPI == 2) v = fmaxf(v, 0.f);
    if (EPI == 1 || EPI == 3) v += b2f(res[(size_t)m * ldr + col]);
    if (EPI == 3)
      ((float*)Cout)[(size_t)m * ldc + col] = v;
    else
      ((unsigned short*)Cout)[(size_t)m * ldc + col] = f2b(v);
  }
}

// ===================== attention: 32x32 MFMA flash, T14 reg-staged =====================
// 512 blocks (XCD-swizzled), 4 waves; wave owns 32 q-rows; KVBLK=64.
#define KLD 40
#define VLD 72
__global__ __launch_bounds__(256, 2) void attn2(
    const unsigned short* __restrict__ Qg,   // [8192][256]
    const unsigned short* __restrict__ KVg,  // [8192][512]: K cols 0..255, V cols 256..511
    unsigned short* __restrict__ O1) {       // [8192][256]
  __shared__ __align__(16) unsigned short Ks[64 * KLD];
  __shared__ __align__(16) unsigned short Vs[32 * VLD];
  const int tid = threadIdx.x, lane = tid & 63, wid = tid >> 6;
  const int l31 = lane & 31, g2 = lane >> 5;
  // XCD-bijective swizzle: 64 consecutive work ids (4 full (b,h) groups) per XCD
  const int w = (blockIdx.x >> 3) + (blockIdx.x & 7) * 64;
  const int b = w >> 7, h = (w >> 4) & 7, qt = w & 15;
  const int row0 = b * 2048 + qt * 128;
  const int qrow = row0 + wid * 32 + l31;

  // Q fragments (B-operand), pre-scaled by 1/sqrt(32)*log2(e)
  const float SCL2 = 0.17677669529663687f * 1.4426950408889634f;
  bf16x8 qf0, qf1;
  {
    const unsigned short* qp = Qg + (size_t)qrow * 256 + h * 32 + g2 * 8;
    #pragma unroll
    for (int dc = 0; dc < 2; ++dc) {
      ushort4 r0 = *(const ushort4*)(qp + dc * 16);
      ushort4 r1 = *(const ushort4*)(qp + dc * 16 + 4);
      union { unsigned short s[8]; bf16x8 v; } u;
      u.s[0] = f2b(b2f(r0.x) * SCL2); u.s[1] = f2b(b2f(r0.y) * SCL2);
      u.s[2] = f2b(b2f(r0.z) * SCL2); u.s[3] = f2b(b2f(r0.w) * SCL2);
      u.s[4] = f2b(b2f(r1.x) * SCL2); u.s[5] = f2b(b2f(r1.y) * SCL2);
      u.s[6] = f2b(b2f(r1.z) * SCL2); u.s[7] = f2b(b2f(r1.w) * SCL2);
      if (dc == 0) qf0 = u.v; else qf1 = u.v;
    }
  }

  const int ksr = tid >> 2, ksc = (tid & 3) * 8;
  const unsigned short* srcK = KVg + (size_t)(b * 2048 + ksr) * 512 + h * 32 + ksc;
  const int vd = tid & 31, vk = (tid >> 5) * 8;
  const unsigned short* srcV = KVg + (size_t)(b * 2048 + vk) * 512 + 256 + h * 32 + vd;

  // prologue: load tile 0 into regs
  uint4 kreg = *(const uint4*)srcK;
  unsigned short va[8];
  #pragma unroll
  for (int j = 0; j < 8; ++j) va[j] = srcV[j * 512];

  f32x16 oacc = Z16;
  float mrun = -INFINITY, lrun = 0.f;

  for (int kt = 0; kt < 2048; kt += 64) {
    // write staged regs -> LDS
    *(uint4*)&Ks[ksr * KLD + ksc] = kreg;
    {
      uint4 wv;
      wv.x = (uint32_t)va[0] | ((uint32_t)va[1] << 16);
      wv.y = (uint32_t)va[2] | ((uint32_t)va[3] << 16);
      wv.z = (uint32_t)va[4] | ((uint32_t)va[5] << 16);
      wv.w = (uint32_t)va[6] | ((uint32_t)va[7] << 16);
      *(uint4*)&Vs[vd * VLD + vk] = wv;
    }
    __syncthreads();  // (a) staged tile visible

    // T14: issue next tile's global loads now; consumed next iteration
    if (kt + 64 < 2048) {
      srcK += 64 * 512;
      kreg = *(const uint4*)srcK;
      srcV += 64 * 512;
      #pragma unroll
      for (int j = 0; j < 8; ++j) va[j] = srcV[j * 512];
    }

    // S^T = K @ Q^T (pre-scaled, log2 domain)
    f32x16 p0 = Z16, p1 = Z16;
    {
      bf16x8 k00 = *(const bf16x8*)&Ks[l31 * KLD + g2 * 8];
      bf16x8 k01 = *(const bf16x8*)&Ks[l31 * KLD + 16 + g2 * 8];
      bf16x8 k10 = *(const bf16x8*)&Ks[(32 + l31) * KLD + g2 * 8];
      bf16x8 k11 = *(const bf16x8*)&Ks[(32 + l31) * KLD + 16 + g2 * 8];
      p0 = MFMA32(k00, qf0, p0);
      p0 = MFMA32(k01, qf1, p0);
      p1 = MFMA32(k10, qf0, p1);
      p1 = MFMA32(k11, qf1, p1);
    }

    // online softmax with defer-max (THR=8 in log2 units)
    float tmax = p0[0];
    #pragma unroll
    for (int i = 1; i < 16; ++i) tmax = fmaxf(tmax, p0[i]);
    #pragma unroll
    for (int i = 0; i < 16; ++i) tmax = fmaxf(tmax, p1[i]);
    tmax = fmaxf(tmax, __shfl_xor(tmax, 32));
    const bool skip = __all(tmax <= mrun + 8.0f) != 0;
    const float mnew = skip ? mrun : fmaxf(mrun, tmax);
    float rsum = 0.f;
    #pragma unroll
    for (int i = 0; i < 16; ++i) { p0[i] = __builtin_amdgcn_exp2f(p0[i] - mnew); rsum += p0[i]; }
    #pragma unroll
    for (int i = 0; i < 16; ++i) { p1[i] = __builtin_amdgcn_exp2f(p1[i] - mnew); rsum += p1[i]; }
    rsum += __shfl_xor(rsum, 32);
    if (skip) {
      lrun += rsum;
    } else {
      const float corr = __builtin_amdgcn_exp2f(mrun - mnew);
      lrun = lrun * corr + rsum;
      #pragma unroll
      for (int i = 0; i < 16; ++i) oacc[i] *= corr;
      mrun = mnew;
    }

    // PV: O^T += V^T @ P^T (cvt_pk pack + xor32 regroup)
    #pragma unroll
    for (int rb = 0; rb < 2; ++rb) {
      const f32x16& pp = rb ? p1 : p0;
      #pragma unroll
      for (int c = 0; c < 2; ++c) {
        uint32_t A0 = cvtpk(pp[8 * c + 0], pp[8 * c + 1]);
        uint32_t A1 = cvtpk(pp[8 * c + 2], pp[8 * c + 3]);
        uint32_t B0 = cvtpk(pp[8 * c + 4], pp[8 * c + 5]);
        uint32_t B1 = cvtpk(pp[8 * c + 6], pp[8 * c + 7]);
        uint32_t pA0 = (uint32_t)__shfl_xor((int)A0, 32);
        uint32_t pB0 = (uint32_t)__shfl_xor((int)B0, 32);
        uint32_t pA1 = (uint32_t)__shfl_xor((int)A1, 32);
        uint32_t pB1 = (uint32_t)__shfl_xor((int)B1, 32);
        union { uint32_t u[4]; bf16x8 v; } fr;
        fr.u[0] = g2 ? pB0 : A0;
        fr.u[1] = g2 ? pB1 : A1;
        fr.u[2] = g2 ? B0 : pA0;
        fr.u[3] = g2 ? B1 : pA1;
        bf16x8 vf = *(const bf16x8*)&Vs[l31 * VLD + rb * 32 + c * 16 + g2 * 8];
        oacc = MFMA32(vf, fr.v, oacc);
      }
    }
    __syncthreads();  // (b) all LDS reads done; drains prefetch (hidden under compute)
  }

  // epilogue: O1 = Q + O^T/l
  const float inv = 1.f / lrun;
  const unsigned short* qres = Qg + (size_t)qrow * 256 + h * 32;
  unsigned short* op = O1 + (size_t)qrow * 256 + h * 32;
  #pragma unroll
  for (int j = 0; j < 4; ++j) {
    const int d0 = 8 * j + 4 * g2;
    uint2 qv = *(const uint2*)(qres + d0);
    float r0 = b2f((unsigned short)(qv.x & 0xffff)) + oacc[4 * j + 0] * inv;
    float r1 = b2f((unsigned short)(qv.x >> 16))    + oacc[4 * j + 1] * inv;
    float r2 = b2f((unsigned short)(qv.y & 0xffff)) + oacc[4 * j + 2] * inv;
    float r3 = b2f((unsigned short)(qv.y >> 16))    + oacc[4 * j + 3] * inv;
    uint2 wv; wv.x = pk2(r0, r1); wv.y = pk2(r2, r3);
    *(uint2*)(op + d0) = wv;
  }
}

// ===================== LayerNorm (bf16 in/out) =====================
__global__ __launch_bounds__(256) void ln_k(
    const unsigned short* __restrict__ X, const float* __restrict__ gw,
    const float* __restrict__ bw, unsigned short* __restrict__ Y) {
  const int wid = threadIdx.x >> 6, lane = threadIdx.x & 63;
  const int row = blockIdx.x * 4 + wid;
  ushort4 xv = *(const ushort4*)(X + (size_t)row * 256 + lane * 4);
  float x0 = b2f(xv.x), x1 = b2f(xv.y), x2 = b2f(xv.z), x3 = b2f(xv.w);
  float s = x0 + x1 + x2 + x3;
  float sq = x0 * x0 + x1 * x1 + x2 * x2 + x3 * x3;
  #pragma unroll
  for (int off = 32; off >= 1; off >>= 1) {
    s += __shfl_xor(s, off);
    sq += __shfl_xor(sq, off);
  }
  const float mean = s * (1.f / 256.f);
  const float var = sq * (1.f / 256.f) - mean * mean;
  const float rstd = rsqrtf(var + 1e-5f);
  float4 gv = *(const float4*)&gw[lane * 4];
  float4 bv = *(const float4*)&bw[lane * 4];
  ushort4 o;
  o.x = f2b((x0 - mean) * rstd * gv.x + bv.x);
  o.y = f2b((x1 - mean) * rstd * gv.y + bv.y);
  o.z = f2b((x2 - mean) * rstd * gv.z + bv.z);
  o.w = f2b((x3 - mean) * rstd * gv.w + bv.w);
  *(ushort4*)(Y + (size_t)row * 256 + lane * 4) = o;
}

// ===================== launch =====================
extern "C" void kernel_launch(void* const* d_in, const int* in_sizes, int n_in,
                              void* d_out, int out_size, void* d_ws, size_t ws_size,
                              hipStream_t stream) {
  (void)in_sizes; (void)n_in; (void)out_size; (void)ws_size;
  const float* q = (const float*)d_in[0];
  const float* x = (const float*)d_in[1];
  const float* Wq = (const float*)d_in[2];
  const float* bq = (const float*)d_in[3];
  const float* Wk = (const float*)d_in[4];
  const float* bk = (const float*)d_in[5];
  const float* Wv = (const float*)d_in[6];
  const float* bv = (const float*)d_in[7];
  const float* Wo = (const float*)d_in[8];
  const float* bo = (const float*)d_in[9];
  const float* Wm = (const float*)d_in[10];
  const float* bm = (const float*)d_in[11];
  const float* We = (const float*)d_in[12];
  const float* be = (const float*)d_in[13];
  const float* g0 = (const float*)d_in[14];
  const float* b0 = (const float*)d_in[15];
  const float* g1 = (const float*)d_in[16];
  const float* b1 = (const float*)d_in[17];
  float* out = (float*)d_out;

  uint8_t* ws = (uint8_t*)d_ws;
  unsigned short* WqT  = (unsigned short*)(ws + 0);         // 128 KB
  unsigned short* WkvT = (unsigned short*)(ws + 131072);    // 256 KB
  unsigned short* WoT  = (unsigned short*)(ws + 393216);    // 128 KB
  unsigned short* WmT  = (unsigned short*)(ws + 524288);    // 512 KB
  unsigned short* WeT  = (unsigned short*)(ws + 1048576);   // 512 KB
  float*          bkv  = (float*)(ws + 1572864);            // 2 KB
  unsigned short* qh   = (unsigned short*)(ws + 1576960);   // 4 MB -> O1n
  unsigned short* xh   = (unsigned short*)(ws + 5771264);   // 4 MB -> O2
  unsigned short* Qb   = (unsigned short*)(ws + 9965568);   // 4 MB -> O2n
  unsigned short* KVb  = (unsigned short*)(ws + 14159872);  // 8 MB -> Mb(lo)
  unsigned short* O1   = (unsigned short*)(ws + 22548480);  // 4 MB -> Mb(mid)
  unsigned short* O1n  = qh;
  unsigned short* O2   = xh;
  unsigned short* O2n  = Qb;
  unsigned short* Mb   = KVb;  // [8192][1024] bf16, 16 MB (needs ws >= 30937088)

  // all preprocessing in one dispatch
  prep<<<2241, 256, 0, stream>>>(q, x, qh, xh, Wq, Wk, Wv, Wo, Wm, We,
                                 WqT, WkvT, WoT, WmT, WeT, bk, bv, bkv);

  // projections
  gemm_small<0><<<dim3(128, 4), 256, 0, stream>>>(qh, 256, WqT, 256, bq, nullptr, 0, Qb, 256, 256);
  gemm_big<0><<<dim3(64, 8), 256, 0, stream>>>(xh, 256, WkvT, 256, bkv, nullptr, 0, KVb, 512, 256);

  // attention + Q residual
  attn2<<<512, 256, 0, stream>>>(Qb, KVb, O1);

  // LN0
  ln_k<<<2048, 256, 0, stream>>>(O1, g0, b0, O1n);
  // O2 = O1n + relu(O1n @ Wo + bo)
  gemm_small<1><<<dim3(128, 4), 256, 0, stream>>>(O1n, 256, WoT, 256, bo, O1n, 256, O2, 256, 256);
  // LN1
  ln_k<<<2048, 256, 0, stream>>>(O2, g1, b1, O2n);

  // MLP: M = relu(O2n @ Wm + bm)  (full F=1024)
  gemm_big<2><<<dim3(64, 16), 256, 0, stream>>>(O2n, 256, WmT, 256, bm, nullptr, 0, Mb, 1024, 256);
  // out = M @ We + be + O2  (fp32, K=1024)
  gemm_small<3><<<dim3(128, 4), 256, 0, stream>>>(Mb, 1024, WeT, 1024, be, O2, 256, out, 256, 1024);
}